// Round 9
// baseline (75.111 us; speedup 1.0000x reference)
//
#include <hip/hip_runtime.h>
#include <hip/hip_bf16.h>
#include <math.h>

// Problem dims (fixed)
#define BB 4
#define TT 4096
#define DM 1024
#define DS 256
#define MROWS (BB*TT)        // 16384

// Scan chunking
#define LCH 32
#define NCH (TT/LCH)         // 128

#define BM 128

typedef __attribute__((ext_vector_type(8))) _Float16 half8v;
typedef __attribute__((ext_vector_type(2))) _Float16 half2v;
typedef __attribute__((ext_vector_type(4))) float float4v;

__device__ __forceinline__ float sigmoidf_dev(float x) {
    return 1.0f / (1.0f + expf(-x));
}

__device__ __forceinline__ half2v cvt2_rtz(float a, float b) {
    auto r = __builtin_amdgcn_cvt_pkrtz(a, b);     // __fp16 ext_vector(2)
    union { decltype(r) i; half2v o; } cv;
    cv.i = r;
    return cv.o;
}

// async global->LDS, 16 bytes per lane; dest linear (uniform + lane*16)
__device__ __forceinline__ void gload16(const void* g, void* l) {
    __builtin_amdgcn_global_load_lds(
        (const __attribute__((address_space(1))) void*)g,
        (__attribute__((address_space(3))) void*)l, 16, 0, 0);
}

// ---------------- weights -> fp16, transposed to [N][K] ----------------
__global__ __launch_bounds__(256) void cvt_weights(
    const float* __restrict__ W1, _Float16* __restrict__ T1,
    const float* __restrict__ W2, _Float16* __restrict__ T2)
{
    const int half = blockIdx.x >> 10;                   // 0: W_in, 1: W_out
    int idx = (blockIdx.x & 1023) * 256 + threadIdx.x;   // over N*K = 262144
    const float* W = half ? W2 : W1;
    _Float16* T = half ? T2 : T1;
    const int K = half ? DS : DM;
    const int N = half ? DM : DS;
    int n = idx / K, k = idx - n * K;
    T[idx] = (_Float16)W[(size_t)k * N + n];
}

// ---------------- GEMM1 (fused): gu = gamma*(x @ W_in^T[n][k] + b_in), + chunk partials ----------------
// A = x fp32 [M][1024] staged raw to LDS (global_load_lds), cvt->fp16 at frag read (pkrtz).
// Bt = w1t fp16 [256][1024]. 256 thr, 4 waves 2x2, tile 128x64, BK=32.
// A LDS rows: 8 chunks x 16B, slot ch' holds chunk ch'^(row&7)  (pre-swizzled source).
// B LDS rows: 4 chunks x 16B, slot ch' holds chunk ch'^((row>>1)&3).
__global__ __launch_bounds__(256) void gemm1_fused(
    const float* __restrict__ x, const _Float16* __restrict__ Bt,
    float* __restrict__ gu,
    const float* __restrict__ bias, const float* __restrict__ scale,
    const float* __restrict__ lam, float* __restrict__ csum)
{
    // LDS: A fp32 2 x 16KB @0 ; B fp16 2 x 4KB @32768 ; epilogue tile 34816 <= 40960
    __shared__ char smem[40960];
    constexpr int K = DM;        // 1024
    constexpr int BN = 64, BK = 32, NF = 2, WCOLS = 32;

    const int nwg = gridDim.x;                  // 512
    const int bid = blockIdx.x;
    const int wgid = (bid & 7) * (nwg >> 3) + (bid >> 3);
    const int GN = DS / BN;                     // 4
    const int bm = wgid / GN;
    const int bn = wgid - bm * GN;

    const int tid  = threadIdx.x;
    const int lane = tid & 63;
    const int wv   = tid >> 6;
    const int wr   = wv >> 1;
    const int wc   = wv & 1;
    const int lrow = lane & 15;
    const int q16  = lane >> 4;

    const int NT = K / BK;                      // 32
    float4v acc[4][NF] = {};

#define STAGE1(T, Q)                                                              \
    do {                                                                          \
        const int k0_ = (T) * BK;                                                 \
        _Pragma("unroll")                                                         \
        for (int p = 0; p < 4; p++) {                                             \
            int c = tid + p * 256, r = c >> 3, chp = c & 7;                       \
            const float* g = x + (size_t)(bm * BM + r) * K + k0_                  \
                               + ((chp ^ (r & 7)) << 2);                          \
            gload16(g, smem + (Q) * 16384 + c * 16);                              \
        }                                                                         \
        {                                                                         \
            int c = tid, r = c >> 2, chp = c & 3;                                 \
            const _Float16* g = Bt + (size_t)(bn * BN + r) * K + k0_              \
                                   + ((chp ^ ((r >> 1) & 3)) << 3);               \
            gload16(g, smem + 32768 + (Q) * 4096 + c * 16);                       \
        }                                                                         \
    } while (0)

    STAGE1(0, 0);
    __syncthreads();

    for (int t = 0; t < NT; ++t) {
        const int Q = t & 1;
        if (t + 1 < NT) STAGE1(t + 1, Q ^ 1);

        // ---- A frags: fp32 in LDS -> fp16 regs ----
        union { half2v h2[4]; half8v h8; } a[4];
        half8v b[NF];
#pragma unroll
        for (int i = 0; i < 4; i++) {
            int row = wr * 64 + i * 16 + lrow;
            const char* ab = smem + Q * 16384 + row * 128;
            int s = row & 7;
            float4 fa = *(const float4*)(ab + (((2 * q16)     ^ s) << 4));
            float4 fb = *(const float4*)(ab + (((2 * q16 + 1) ^ s) << 4));
            a[i].h2[0] = cvt2_rtz(fa.x, fa.y);
            a[i].h2[1] = cvt2_rtz(fa.z, fa.w);
            a[i].h2[2] = cvt2_rtz(fb.x, fb.y);
            a[i].h2[3] = cvt2_rtz(fb.z, fb.w);
        }
#pragma unroll
        for (int j = 0; j < NF; j++) {
            int row = wc * WCOLS + j * 16 + lrow;
            b[j] = *(const half8v*)(smem + 32768 + Q * 4096 +
                                    ((row * 4 + (q16 ^ ((row >> 1) & 3))) << 4));
        }

#pragma unroll
        for (int i = 0; i < 4; i++)
#pragma unroll
            for (int j = 0; j < NF; j++)
                acc[i][j] = __builtin_amdgcn_mfma_f32_16x16x32_f16(a[i].h8, b[j], acc[i][j], 0, 0, 0);

        __syncthreads();
    }

    // ---- epilogue: write gu + stash tile in LDS for scan partials ----
    float* gul = (float*)smem;    // [128][68]
#pragma unroll
    for (int j = 0; j < NF; j++) {
        int col = bn * BN + wc * WCOLS + j * 16 + lrow;
        float bi = bias[col];
        float sc = scale[col];
#pragma unroll
        for (int i = 0; i < 4; i++) {
            int r0 = bm * BM + wr * 64 + i * 16 + q16 * 4;
#pragma unroll
            for (int reg = 0; reg < 4; reg++) {
                float v = (acc[i][j][reg] + bi) * sc;
                gu[(size_t)(r0 + reg) * DS + col] = v;
                int lr = wr * 64 + i * 16 + q16 * 4 + reg;
                int lc = wc * WCOLS + j * 16 + lrow;
                gul[lr * 68 + lc] = v;
            }
        }
    }

    __syncthreads();
    // 256 threads: one (chunk, channel) scan each; BM=128 -> 4 chunks of 32.
    const int lc = tid >> 6;
    const int ch = tid & 63;
    const int gcol = bn * BN + ch;
    const float d = sigmoidf_dev(lam[gcol]);
    float h = 0.0f;
#pragma unroll
    for (int rr = 0; rr < LCH; rr++)
        h = fmaf(d, h, gul[(lc * LCH + rr) * 68 + ch]);
    const int row0 = bm * BM;
    const int b    = row0 >> 12;
    const int gch  = ((row0 & 4095) >> 5) + lc;
    csum[((size_t)b * NCH + gch) * DS + gcol] = h;
#undef STAGE1
}

// ---------------- GEMM2: y = h @ W_out + b_out ----------------
// A = hf fp16 [M][256], Bt = w2t fp16 [1024][256]. Tile 128x128, BK=64.
__global__ __launch_bounds__(256) void gemm2_f16(
    const _Float16* __restrict__ A, const _Float16* __restrict__ Bt,
    float* __restrict__ C, const float* __restrict__ bias)
{
    constexpr int BN = 128, BK = 64, NF = 4, WCOLS = 64;
    constexpr int K = DS;                         // 256
    constexpr int ABYTES = BM * BK * 2;           // 16384
    constexpr int BUFB = ABYTES + BN * BK * 2;    // 32768
    __shared__ char smem[2 * BUFB];

    const int nwg = gridDim.x;                    // 1024
    const int bid = blockIdx.x;
    const int wgid = (bid & 7) * (nwg >> 3) + (bid >> 3);
    const int GN = DM / BN;                       // 8
    const int bm = wgid / GN;
    const int bn = wgid - bm * GN;

    const int tid  = threadIdx.x;
    const int lane = tid & 63;
    const int wv   = tid >> 6;
    const int wr   = wv >> 1;
    const int wc   = wv & 1;
    const int lrow = lane & 15;
    const int q16  = lane >> 4;

    const int NT = K / BK;                        // 4
    float4v acc[4][NF] = {};

#define STAGE2(T, Q)                                                              \
    do {                                                                          \
        const int k0_ = (T) * BK;                                                 \
        char* base_ = smem + (Q) * BUFB;                                          \
        _Pragma("unroll")                                                         \
        for (int p = 0; p < 4; p++) {                                             \
            int c = tid + p * 256, r = c >> 3, chp = c & 7;                       \
            const _Float16* g = A + (size_t)(bm * BM + r) * K + k0_               \
                                  + ((chp ^ (r & 7)) << 3);                       \
            gload16(g, base_ + c * 16);                                           \
        }                                                                         \
        _Pragma("unroll")                                                         \
        for (int p = 0; p < 4; p++) {                                             \
            int c = tid + p * 256, r = c >> 3, chp = c & 7;                       \
            const _Float16* g = Bt + (size_t)(bn * BN + r) * K + k0_              \
                                   + ((chp ^ (r & 7)) << 3);                      \
            gload16(g, base_ + ABYTES + c * 16);                                  \
        }                                                                         \
    } while (0)

    STAGE2(0, 0);
    __syncthreads();

    for (int t = 0; t < NT; ++t) {
        const int Q = t & 1;
        if (t + 1 < NT) STAGE2(t + 1, Q ^ 1);

        char* const rb = smem + Q * BUFB;
        half8v a[4][2], b[NF][2];
#pragma unroll
        for (int i = 0; i < 4; i++) {
            int row = wr * 64 + i * 16 + lrow;
#pragma unroll
            for (int ss = 0; ss < 2; ss++) {
                int ch = ss * 4 + q16;
                a[i][ss] = *(const half8v*)(rb + ((row * 8 + (ch ^ (row & 7))) << 4));
            }
        }
#pragma unroll
        for (int j = 0; j < NF; j++) {
            int row = wc * WCOLS + j * 16 + lrow;
#pragma unroll
            for (int ss = 0; ss < 2; ss++) {
                int ch = ss * 4 + q16;
                b[j][ss] = *(const half8v*)(rb + ABYTES + ((row * 8 + (ch ^ (row & 7))) << 4));
            }
        }

#pragma unroll
        for (int ss = 0; ss < 2; ss++)
#pragma unroll
            for (int i = 0; i < 4; i++)
#pragma unroll
                for (int j = 0; j < NF; j++)
                    acc[i][j] = __builtin_amdgcn_mfma_f32_16x16x32_f16(a[i][ss], b[j][ss], acc[i][j], 0, 0, 0);

        __syncthreads();
    }

#pragma unroll
    for (int j = 0; j < NF; j++) {
        int col = bn * BN + wc * WCOLS + j * 16 + lrow;
        float bi = bias[col];
#pragma unroll
        for (int i = 0; i < 4; i++) {
            int r0 = bm * BM + wr * 64 + i * 16 + q16 * 4;
#pragma unroll
            for (int reg = 0; reg < 4; reg++)
                C[(size_t)(r0 + reg) * DM + col] = acc[i][j][reg] + bi;
        }
    }
#undef STAGE2
}

// ---------------- scan kernels ----------------
__global__ __launch_bounds__(256) void carry_scan(
    const float* __restrict__ csum, const float* __restrict__ state,
    const float* __restrict__ lam, float* __restrict__ carry, float* __restrict__ hlast)
{
    const int s = threadIdx.x;
    const int b = blockIdx.x;
    const float d = sigmoidf_dev(lam[s]);
    float dL = d;
#pragma unroll
    for (int i = 0; i < 5; i++) dL *= dL;   // d^32
    float H = state[(size_t)b * DS + s];
#pragma unroll 8
    for (int k = 0; k < NCH; k++) {
        carry[((size_t)b * NCH + k) * DS + s] = H;
        H = fmaf(dL, H, csum[((size_t)b * NCH + k) * DS + s]);
    }
    hlast[(size_t)b * DS + s] = H;
}

// recompute with carry; emit h as fp16 (feeds GEMM2 directly)
__global__ __launch_bounds__(256) void scan_final(
    const float* __restrict__ gu, const float* __restrict__ lam,
    const float* __restrict__ carry, _Float16* __restrict__ hf)
{
    const int s = threadIdx.x;
    const int chunk = blockIdx.x;
    const int b = blockIdx.y;
    const float d = sigmoidf_dev(lam[s]);
    const size_t base = ((size_t)b * TT + (size_t)chunk * LCH) * DS + s;
    const float* p = gu + base;
    _Float16* ph = hf + base;
    float h = carry[((size_t)b * NCH + chunk) * DS + s];
#pragma unroll
    for (int t = 0; t < LCH; t++) {
        h = fmaf(d, h, p[(size_t)t * DS]);
        ph[(size_t)t * DS] = (_Float16)h;
    }
}

extern "C" void kernel_launch(void* const* d_in, const int* in_sizes, int n_in,
                              void* d_out, int out_size, void* d_ws, size_t ws_size,
                              hipStream_t stream) {
    const float* x     = (const float*)d_in[0];
    const float* state = (const float*)d_in[1];
    const float* W_in  = (const float*)d_in[2];
    const float* b_in  = (const float*)d_in[3];
    const float* lam   = (const float*)d_in[4];
    const float* gamma = (const float*)d_in[5];
    const float* W_out = (const float*)d_in[6];
    const float* b_out = (const float*)d_in[7];

    float* y     = (float*)d_out;
    float* hlast = y + (size_t)MROWS * DM;

    char* ws = (char*)d_ws;
    const size_t MB = 1024 * 1024;
    float*     gu    = (float*)(ws);                           // 16 MB
    float*     csum  = (float*)(ws + 16 * MB);                 // 512 KB
    float*     carry = (float*)(ws + 16 * MB + 512 * 1024);    // 512 KB
    _Float16*  hf    = (_Float16*)(ws + 17 * MB);              // 8 MB  [M][DS]
    _Float16*  w1t   = (_Float16*)(ws + 25 * MB);              // 512 KB [DS][DM]
    _Float16*  w2t   = (_Float16*)(ws + 25 * MB + 512 * 1024); // 512 KB [DM][DS]

    cvt_weights<<<dim3(2048), dim3(256), 0, stream>>>(W_in, w1t, W_out, w2t);

    // GEMM1 (+fused chunk partials): reads x fp32 directly
    gemm1_fused<<<dim3((MROWS / BM) * (DS / 64)), dim3(256), 0, stream>>>(
        x, w1t, gu, b_in, gamma, lam, csum);

    carry_scan<<<dim3(BB), dim3(256), 0, stream>>>(csum, state, lam, carry, hlast);
    scan_final<<<dim3(NCH, BB), dim3(256), 0, stream>>>(gu, lam, carry, hf);

    // GEMM2: y = h @ W_out + b_out
    gemm2_f16<<<dim3((MROWS / BM) * (DM / 128)), dim3(256), 0, stream>>>(
        hf, w2t, y, b_out);
}